// Round 5
// baseline (1864.650 us; speedup 1.0000x reference)
//
#include <hip/hip_runtime.h>

#define NN 100000
#define EE 1600000
#define RRR 8
#define NSEG (NN*RRR)
#define F 128
#define NBK 196            // ceil(NN/512) dst-buckets of 512 nodes
#define NT 64              // nodes per fused block
#define BNEPS 1e-5f

typedef __attribute__((ext_vector_type(8))) short bf16x8;
typedef __attribute__((ext_vector_type(8))) unsigned short u16x8;
typedef __attribute__((ext_vector_type(4))) float f32x4;

static __device__ __forceinline__ unsigned short bf16r(float f) {
  unsigned u = __float_as_uint(f);
  u += 0x7fffu + ((u >> 16) & 1u);
  return (unsigned short)(u >> 16);
}
static __device__ __forceinline__ float b2f(unsigned short s) {
  return __uint_as_float((unsigned)s << 16);
}
// XOR-swizzle on linear LDS byte address (16B granules, 256B rows)
static __device__ __forceinline__ int swz(int a) {
  return a ^ (((a >> 8) & 7) << 4);
}

// ----------------------- bucketed graph preprocessing -----------------------
__global__ void k_hist(const int* __restrict__ dst, unsigned* __restrict__ bhist) {
  __shared__ unsigned h[NBK];
  int t = threadIdx.x;
  if (t < NBK) h[t] = 0;
  __syncthreads();
  for (int e = blockIdx.x*256 + t; e < EE; e += gridDim.x*256)
    atomicAdd(&h[((unsigned)dst[e]) >> 9], 1u);
  __syncthreads();
  if (t < NBK) atomicAdd(&bhist[t], h[t]);
}

__global__ void k_scanb(const unsigned* __restrict__ bhist, unsigned* __restrict__ boff) {
  __shared__ unsigned s[256];
  int t = threadIdx.x;
  unsigned v = (t < NBK) ? bhist[t] : 0u;
  s[t] = v;
  __syncthreads();
  for (int d = 1; d < 256; d <<= 1) {
    unsigned u = (t >= d) ? s[t-d] : 0u;
    __syncthreads();
    s[t] += u;
    __syncthreads();
  }
  if (t < NBK) boff[t] = s[t] - v;
  if (t == NBK-1) boff[NBK] = s[t];
}

// pack (local_seg, src) into one u32: lseg = (dst&511)*8+et < 4096 (12b), src < 2^17
__global__ void k_scatter(const int* __restrict__ src, const int* __restrict__ dst,
                          const int* __restrict__ et, const unsigned* __restrict__ boff,
                          unsigned* __restrict__ bfill, unsigned* __restrict__ ebuf) {
  int e = blockIdx.x*256 + threadIdx.x;
  if (e < EE) {
    int d = dst[e];
    int b = ((unsigned)d) >> 9;
    unsigned pos = boff[b] + atomicAdd(&bfill[b], 1u);
    ebuf[pos] = (((unsigned)((d & 511)*RRR + et[e])) << 17) | (unsigned)src[e];
  }
}

// one block per bucket: LDS count + LDS scan + local fill (csr window ~32KB)
__global__ __launch_bounds__(256) void k_bucket(const unsigned* __restrict__ boff,
    const unsigned* __restrict__ ebuf, unsigned* __restrict__ off,
    unsigned* __restrict__ cnt, int* __restrict__ csr) {
  __shared__ unsigned lcnt[4096];
  __shared__ unsigned loff[4096];
  __shared__ unsigned wsum[256];
  int b = blockIdx.x, t = threadIdx.x;
  unsigned s0 = boff[b], e0 = boff[b+1];
  for (int i = t; i < 4096; i += 256) lcnt[i] = 0;
  __syncthreads();
  for (unsigned i = s0 + t; i < e0; i += 256)
    atomicAdd(&lcnt[ebuf[i] >> 17], 1u);
  __syncthreads();
  // exclusive scan of 4096: 16 serial per thread + block scan
  unsigned run = 0, tmp[16];
  int base16 = t*16;
#pragma unroll
  for (int j = 0; j < 16; j++) { tmp[j] = run; run += lcnt[base16 + j]; }
  wsum[t] = run;
  __syncthreads();
  for (int d = 1; d < 256; d <<= 1) {
    unsigned u = (t >= d) ? wsum[t-d] : 0u;
    __syncthreads();
    wsum[t] += u;
    __syncthreads();
  }
  unsigned tb = wsum[t] - run;
#pragma unroll
  for (int j = 0; j < 16; j++) loff[base16 + j] = tb + tmp[j];
  __syncthreads();
  int gbase = b*4096;
  for (int i = t; i < 4096; i += 256) {
    int gseg = gbase + i;
    if (gseg < NSEG) { off[gseg] = s0 + loff[i]; cnt[gseg] = lcnt[i]; }
  }
  // reuse lcnt as fill cursors
  for (int i = t; i < 4096; i += 256) lcnt[i] = 0;
  __syncthreads();
  for (unsigned i = s0 + t; i < e0; i += 256) {
    unsigned p = ebuf[i];
    unsigned ls = p >> 17;
    unsigned r = atomicAdd(&lcnt[ls], 1u);
    csr[s0 + loff[ls] + r] = (int)(p & 0x1FFFFu);
  }
}

// x (f32) -> xb (bf16)
__global__ void k_cvt(const float* __restrict__ x, unsigned short* __restrict__ xb) {
  int i = blockIdx.x*256 + threadIdx.x;
  if (i < NN*32) {
    float4 v = ((const float4*)x)[i];
    ushort4 o;
    o.x = bf16r(v.x); o.y = bf16r(v.y); o.z = bf16r(v.z); o.w = bf16r(v.w);
    ((ushort4*)xb)[i] = o;
  }
}

// WB in B-fragment layout (bf16): WB[((kt*8 + ct)*64 + lane)*8 + j]
//   = Wcat[k][o],  k = kt*32 + (lane>>4)*8 + j,  o = ct*16 + (lane&15)
__global__ void k_makeW(const float* __restrict__ basis, const float* __restrict__ comp,
                        const float* __restrict__ root, unsigned short* __restrict__ WB) {
  int kt = blockIdx.x;        // 0..35
  int ct = blockIdx.y;        // 0..7
  int lane = threadIdx.x;     // 0..63
  int o = ct*16 + (lane & 15);
  int kbase = kt*32 + (lane >> 4)*8;
  unsigned short v[8];
#pragma unroll
  for (int j = 0; j < 8; j++) {
    int k = kbase + j;
    float val;
    if (k < 1024) {
      int r = k >> 7, i = k & 127;
      val = 0.f;
#pragma unroll
      for (int bb = 0; bb < 8; bb++)
        val += comp[r*8+bb] * basis[(bb*F + i)*F + o];
    } else {
      val = root[(k - 1024)*F + o];
    }
    v[j] = bf16r(val);
  }
  unsigned short* dstp = WB + ((size_t)(kt*8 + ct)*64 + lane)*8;
#pragma unroll
  for (int j = 0; j < 8; j++) dstp[j] = v[j];
}

// ----------------------- fused agg + GEMM (+BN stats / +L2) -----------------------
// Block = 64 nodes, 256 thr (4 waves). 9 chunks: 8 relation-means + self.
// Gather map: group g = t>>4 (16 lanes) walks rows g*4..g*4+3 SEQUENTIALLY
// (work = sum over segments, not max) -> low divergence, round-4-style MLP.
// MFMA map: wave w = rows w*16..w*16+15, all 128 cols; acc 8 x f32x4.
__global__ __launch_bounds__(256) void k_fused(const unsigned short* __restrict__ hb,
    const unsigned* __restrict__ off, const unsigned* __restrict__ cnt,
    const int* __restrict__ csr, const unsigned short* __restrict__ WB,
    const float* __restrict__ bias, float* __restrict__ outp,
    float* __restrict__ stats, int mode) {
  __shared__ __align__(16) char lds[NT*256];
  __shared__ float s_sum[128], s_sq[128];
  int t = threadIdx.x;
  int lane = t & 63, wave = t >> 6;
  int g = t >> 4, sl = t & 15;
  int rlo = lane & 15, kg = lane >> 4;
  int n0 = blockIdx.x * NT;
  if (mode == 0 && t < 128) { s_sum[t] = 0.f; s_sq[t] = 0.f; }

  f32x4 acc[8];
#pragma unroll
  for (int j = 0; j < 8; j++) acc[j] = (f32x4){0.f, 0.f, 0.f, 0.f};

  for (int c = 0; c < 9; c++) {
    __syncthreads();   // previous chunk's MFMA reads done (covers s_sum zero too)
#pragma unroll
    for (int nn = 0; nn < 4; nn++) {
      int row = g*4 + nn;
      int node = n0 + row;
      int nodec = (node < NN) ? node : NN-1;
      u16x8 o;
      if (c < 8) {
        int seg = nodec*RRR + c;
        unsigned b0 = off[seg], k = cnt[seg];
        float a[8];
#pragma unroll
        for (int u = 0; u < 8; u++) a[u] = 0.f;
        unsigned j = 0;
        for (; j + 2 <= k; j += 2) {
          int iA = csr[b0+j];
          int iB = csr[b0+j+1];
          u16x8 va = *(const u16x8*)&hb[(size_t)iA*F + sl*8];
          u16x8 vb = *(const u16x8*)&hb[(size_t)iB*F + sl*8];
#pragma unroll
          for (int u = 0; u < 8; u++) a[u] += b2f(va[u]) + b2f(vb[u]);
        }
        if (j < k) {
          int iA = csr[b0+j];
          u16x8 va = *(const u16x8*)&hb[(size_t)iA*F + sl*8];
#pragma unroll
          for (int u = 0; u < 8; u++) a[u] += b2f(va[u]);
        }
        float inv = k ? 1.f/(float)k : 0.f;
#pragma unroll
        for (int u = 0; u < 8; u++) o[u] = bf16r(a[u]*inv);
      } else {
        o = *(const u16x8*)&hb[(size_t)nodec*F + sl*8];
      }
      *(u16x8*)(lds + swz(row*256 + sl*16)) = o;
    }
    __syncthreads();
#pragma unroll
    for (int kt = 0; kt < 4; kt++) {
      bf16x8 a = *(const bf16x8*)(lds + swz((wave*16 + rlo)*256 + kt*64 + kg*16));
      const unsigned short* bp = WB + ((size_t)((c*4 + kt)*8)*64 + lane)*8;
#pragma unroll
      for (int ct = 0; ct < 8; ct++) {
        bf16x8 bfr = *(const bf16x8*)(bp + (size_t)ct*64*8);
        acc[ct] = __builtin_amdgcn_mfma_f32_16x16x32_bf16(a, bfr, acc[ct], 0, 0, 0);
      }
    }
  }

  float bv[8];
#pragma unroll
  for (int ct = 0; ct < 8; ct++) bv[ct] = bias[ct*16 + rlo];

  // C/D layout: col = ct*16 + rlo, row-in-wave-tile = kg*4 + i
  if (mode == 0) {
    float psum[8], psq[8];
#pragma unroll
    for (int ct = 0; ct < 8; ct++) { psum[ct] = 0.f; psq[ct] = 0.f; }
#pragma unroll
    for (int i = 0; i < 4; i++) {
      int row = n0 + wave*16 + kg*4 + i;
      if (row < NN) {
        float* orow = outp + (size_t)row*F;
#pragma unroll
        for (int ct = 0; ct < 8; ct++) {
          float y = acc[ct][i] + bv[ct];
          orow[ct*16 + rlo] = y;
          psum[ct] += y;
          psq[ct]  += y*y;
        }
      }
    }
#pragma unroll
    for (int ct = 0; ct < 8; ct++) {
      atomicAdd(&s_sum[ct*16 + rlo], psum[ct]);
      atomicAdd(&s_sq [ct*16 + rlo], psq[ct]);
    }
    __syncthreads();
    if (t < 128) {
      atomicAdd(&stats[t],       s_sum[t]);
      atomicAdd(&stats[128 + t], s_sq[t]);
    }
  } else {
#pragma unroll
    for (int i = 0; i < 4; i++) {
      int row = n0 + wave*16 + kg*4 + i;
      float y[8], ss = 0.f;
#pragma unroll
      for (int ct = 0; ct < 8; ct++) {
        y[ct] = acc[ct][i] + bv[ct];
        ss += y[ct]*y[ct];
      }
#pragma unroll
      for (int m = 1; m < 16; m <<= 1)
        ss += __shfl_xor(ss, m, 64);
      float inv = 1.f / fmaxf(sqrtf(ss), 1e-12f);
      if (row < NN) {
        float* orow = outp + (size_t)row*F;
#pragma unroll
        for (int ct = 0; ct < 8; ct++)
          orow[ct*16 + rlo] = y[ct]*inv;
      }
    }
  }
}

// BN apply + LeakyReLU, writes bf16 table for next layer's gathers
__global__ __launch_bounds__(256) void k_bnapply(const float* __restrict__ h,
    const float* __restrict__ stats, const float* __restrict__ gamma,
    const float* __restrict__ beta, unsigned short* __restrict__ outp) {
  int idx = blockIdx.x*256 + threadIdx.x;
  if (idx >= NN*32) return;
  int row = idx >> 5;
  int c4 = (idx & 31) * 4;
  float4 v  = *(const float4*)&h[(size_t)row*F + c4];
  float4 sm = *(const float4*)&stats[c4];
  float4 sq = *(const float4*)&stats[128 + c4];
  float4 gm = *(const float4*)&gamma[c4];
  float4 bt = *(const float4*)&beta[c4];
  const float invN = 1.f / (float)NN;
  ushort4 o;
  { float m = sm.x*invN; float var = sq.x*invN - m*m; float r0 = rsqrtf(var + BNEPS);
    float z = (v.x - m)*r0*gm.x + bt.x; o.x = bf16r((z > 0.f) ? z : 0.1f*z); }
  { float m = sm.y*invN; float var = sq.y*invN - m*m; float r0 = rsqrtf(var + BNEPS);
    float z = (v.y - m)*r0*gm.y + bt.y; o.y = bf16r((z > 0.f) ? z : 0.1f*z); }
  { float m = sm.z*invN; float var = sq.z*invN - m*m; float r0 = rsqrtf(var + BNEPS);
    float z = (v.z - m)*r0*gm.z + bt.z; o.z = bf16r((z > 0.f) ? z : 0.1f*z); }
  { float m = sm.w*invN; float var = sq.w*invN - m*m; float r0 = rsqrtf(var + BNEPS);
    float z = (v.w - m)*r0*gm.w + bt.w; o.w = bf16r((z > 0.f) ? z : 0.1f*z); }
  *(ushort4*)&outp[(size_t)row*F + c4] = o;
}

// ----------------------------- host launcher -----------------------------
extern "C" void kernel_launch(void* const* d_in, const int* in_sizes, int n_in,
                              void* d_out, int out_size, void* d_ws, size_t ws_size,
                              hipStream_t stream) {
  const float* x      = (const float*)d_in[0];
  const int*   ei     = (const int*)d_in[1];
  const int*   etp    = (const int*)d_in[2];
  const float* basis[3] = {(const float*)d_in[3], (const float*)d_in[7],  (const float*)d_in[11]};
  const float* comp[3]  = {(const float*)d_in[4], (const float*)d_in[8],  (const float*)d_in[12]};
  const float* root[3]  = {(const float*)d_in[5], (const float*)d_in[9],  (const float*)d_in[13]};
  const float* bias[3]  = {(const float*)d_in[6], (const float*)d_in[10], (const float*)d_in[14]};
  const float* gamma[2] = {(const float*)d_in[15], (const float*)d_in[17]};
  const float* beta[2]  = {(const float*)d_in[16], (const float*)d_in[18]};
  const int* srcv = ei;
  const int* dstv = ei + EE;
  float* out = (float*)d_out;

  char* w = (char*)d_ws;
  size_t p = 0;
  auto take = [&](size_t bytes) -> void* {
    void* q = w + p;
    p = (p + bytes + 255) & ~(size_t)255;
    return q;
  };
  unsigned* cnt   = (unsigned*)take((size_t)NSEG*4);
  unsigned* off   = (unsigned*)take((size_t)NSEG*4);
  int*      csr   = (int*)     take((size_t)EE*4);
  unsigned* ebuf  = (unsigned*)take((size_t)EE*4);
  unsigned* bhist = (unsigned*)take((size_t)NBK*4);
  unsigned* boff  = (unsigned*)take((size_t)(NBK+1)*4);
  unsigned* bfill = (unsigned*)take((size_t)NBK*4);
  unsigned short* WB = (unsigned short*)take((size_t)1152*F*2);
  float*    stats = (float*)   take(256*4);
  float*    wsA   = (float*)   take((size_t)NN*F*4);             // f32 conv out
  unsigned short* wsBb = (unsigned short*)take((size_t)NN*F*2);  // bf16 BN out
  unsigned short* xb   = (unsigned short*)take((size_t)NN*F*2);  // bf16 x
  (void)ws_size;

  // -------- bucketed graph preprocessing --------
  hipMemsetAsync(bhist, 0, (size_t)NBK*4, stream);
  hipMemsetAsync(bfill, 0, (size_t)NBK*4, stream);
  k_hist<<<256, 256, 0, stream>>>(dstv, bhist);
  k_scanb<<<1, 256, 0, stream>>>(bhist, boff);
  k_scatter<<<(EE+255)/256, 256, 0, stream>>>(srcv, dstv, etp, boff, bfill, ebuf);
  k_bucket<<<NBK, 256, 0, stream>>>(boff, ebuf, off, cnt, csr);
  k_cvt<<<(NN*32+255)/256, 256, 0, stream>>>(x, xb);

  // -------- 3 layers --------
  int NB = (NN + NT - 1) / NT;
  for (int l = 0; l < 3; l++) {
    const unsigned short* hin = (l == 0) ? xb : wsBb;
    float* hraw = (l == 2) ? out : wsA;
    int mode = (l == 2) ? 1 : 0;
    dim3 gw(36, 8);
    k_makeW<<<gw, 64, 0, stream>>>(basis[l], comp[l], root[l], WB);
    if (l < 2) hipMemsetAsync(stats, 0, 256*4, stream);
    k_fused<<<NB, 256, 0, stream>>>(hin, off, cnt, csr, WB, bias[l], hraw, stats, mode);
    if (l < 2)
      k_bnapply<<<(NN*32+255)/256, 256, 0, stream>>>(hraw, stats, gamma[l], beta[l], wsBb);
  }
}

// Round 6
// 1319.020 us; speedup vs baseline: 1.4137x; 1.4137x over previous
//
#include <hip/hip_runtime.h>

#define NN 100000
#define EE 1600000
#define RRR 8
#define NSEG (NN*RRR)
#define F 128
#define BNEPS 1e-5f

typedef __attribute__((ext_vector_type(8))) short bf16x8;
typedef __attribute__((ext_vector_type(8))) unsigned short u16x8;
typedef __attribute__((ext_vector_type(4))) float f32x4;

static __device__ __forceinline__ unsigned short bf16r(float f) {
  unsigned u = __float_as_uint(f);
  u += 0x7fffu + ((u >> 16) & 1u);
  return (unsigned short)(u >> 16);
}
static __device__ __forceinline__ float b2f(unsigned short s) {
  return __uint_as_float((unsigned)s << 16);
}

// ------------------- preprocessing -------------------
// fused: bf16 convert of x  +  per-(dst,rel) segment count
__global__ __launch_bounds__(256) void k_precnt(const float* __restrict__ x,
    unsigned short* __restrict__ xb, const int* __restrict__ dst,
    const int* __restrict__ et, unsigned* __restrict__ cnt) {
  int idx = blockIdx.x*256 + threadIdx.x;
  if (idx < NN*32) {
    float4 v = ((const float4*)x)[idx];
    ushort4 o;
    o.x = bf16r(v.x); o.y = bf16r(v.y); o.z = bf16r(v.z); o.w = bf16r(v.w);
    ((ushort4*)xb)[idx] = o;
  }
  if (idx < EE)
    atomicAdd(&cnt[dst[idx]*RRR + et[idx]], 1u);
}

__global__ void k_scan1(const unsigned* __restrict__ cnt, unsigned* __restrict__ off,
                        unsigned* __restrict__ bsum) {
  __shared__ unsigned s[256];
  int t = threadIdx.x;
  int base = blockIdx.x*2048 + t*8;
  unsigned loc[8];
  unsigned tot = 0;
#pragma unroll
  for (int j = 0; j < 8; j++) {
    unsigned v = (base+j < NSEG) ? cnt[base+j] : 0u;
    loc[j] = tot;
    tot += v;
  }
  s[t] = tot;
  __syncthreads();
  for (int d = 1; d < 256; d <<= 1) {
    unsigned v = (t >= d) ? s[t-d] : 0u;
    __syncthreads();
    s[t] += v;
    __syncthreads();
  }
  unsigned tbase = s[t] - tot;
#pragma unroll
  for (int j = 0; j < 8; j++)
    if (base+j < NSEG) off[base+j] = tbase + loc[j];
  if (t == 255) bsum[blockIdx.x] = s[255];
}

__global__ void k_scan2(unsigned* bsum, int nb) {
  __shared__ unsigned s[512];
  int t = threadIdx.x;
  unsigned v = (t < nb) ? bsum[t] : 0u;
  s[t] = v;
  __syncthreads();
  for (int d = 1; d < 512; d <<= 1) {
    unsigned u = (t >= d) ? s[t-d] : 0u;
    __syncthreads();
    s[t] += u;
    __syncthreads();
  }
  if (t < nb) bsum[t] = (t == 0) ? 0u : s[t-1];
}

__global__ void k_scan3(unsigned* off, const unsigned* __restrict__ bsum) {
  int i = blockIdx.x*256 + threadIdx.x;
  if (i < NSEG) off[i] += bsum[i >> 11];
}

// fill using off itself as cursor: afterwards off[seg] = segment END;
// consumers recover start = off[seg] - cnt[seg].
__global__ void k_fill(const int* __restrict__ src, const int* __restrict__ dst,
                       const int* __restrict__ et, unsigned* __restrict__ off,
                       int* __restrict__ csr) {
  int e = blockIdx.x*256 + threadIdx.x;
  if (e < EE) {
    int seg = dst[e]*RRR + et[e];
    unsigned pos = atomicAdd(&off[seg], 1u);
    csr[pos] = src[e];
  }
}

// All 3 layers' weights in B-fragment layout, one launch; block(0,0,0)
// also zeroes both BN stats buffers.
// WB3[l][((kt*8 + ct)*64 + lane)*8 + j] = Wcat_l[k][o],
//   k = kt*32 + (lane>>4)*8 + j,  o = ct*16 + (lane&15)
__global__ void k_makeW3(const float* __restrict__ b1, const float* __restrict__ c1,
                         const float* __restrict__ r1, const float* __restrict__ b2,
                         const float* __restrict__ c2, const float* __restrict__ r2,
                         const float* __restrict__ b3, const float* __restrict__ c3,
                         const float* __restrict__ r3, unsigned short* __restrict__ WB3,
                         float* __restrict__ stats) {
  int kt = blockIdx.x, ct = blockIdx.y, l = blockIdx.z;
  int lane = threadIdx.x;
  if (kt == 0 && ct == 0 && l == 0) {
#pragma unroll
    for (int j = 0; j < 8; j++) stats[lane*8 + j] = 0.f;
  }
  const float* basis = (l == 0) ? b1 : (l == 1) ? b2 : b3;
  const float* comp  = (l == 0) ? c1 : (l == 1) ? c2 : c3;
  const float* root  = (l == 0) ? r1 : (l == 1) ? r2 : r3;
  int o = ct*16 + (lane & 15);
  int kbase = kt*32 + (lane >> 4)*8;
  unsigned short v[8];
#pragma unroll
  for (int j = 0; j < 8; j++) {
    int k = kbase + j;
    float val;
    if (k < 1024) {
      int r = k >> 7, i = k & 127;
      val = 0.f;
#pragma unroll
      for (int bb = 0; bb < 8; bb++)
        val += comp[r*8+bb] * basis[(bb*F + i)*F + o];
    } else {
      val = root[(k - 1024)*F + o];
    }
    v[j] = bf16r(val);
  }
  unsigned short* dstp = WB3 + (size_t)l*1152*F + ((size_t)(kt*8 + ct)*64 + lane)*8;
#pragma unroll
  for (int j = 0; j < 8; j++) dstp[j] = v[j];
}

// ------------------- aggregation -------------------
// Block = 32 segments (4 nodes). Group g (16 lanes) interleaves TWO segments
// -> up to 4 independent gathers in flight. Mean = [localnode*8+r][128] bf16
// (no self chunk; gemm reads root-term from hb directly).
__global__ __launch_bounds__(256) void k_agg(const unsigned short* __restrict__ hb,
    const unsigned* __restrict__ off, const unsigned* __restrict__ cnt,
    const int* __restrict__ csr, unsigned short* __restrict__ Mean, int segBase) {
  int t = threadIdx.x;
  int sl = t & 15, c8 = sl*8;
  int g = t >> 4;
  int s0 = segBase + blockIdx.x*32 + 2*g;
  int s1 = s0 + 1;
  unsigned cA = cnt[s0], cB = cnt[s1];
  unsigned bA = off[s0] - cA, bB = off[s1] - cB;
  const unsigned short* hc = hb + c8;
  float aA[8], aB[8];
#pragma unroll
  for (int u = 0; u < 8; u++) { aA[u] = 0.f; aB[u] = 0.f; }
  unsigned jA = 0, jB = 0;
  while (jA < cA || jB < cB) {
    unsigned nA = cA - jA; if (nA > 2) nA = 2;
    unsigned nB = cB - jB; if (nB > 2) nB = 2;
    int i0 = 0, i1 = 0, i2 = 0, i3 = 0;
    if (nA > 0) i0 = csr[bA + jA];
    if (nA > 1) i1 = csr[bA + jA + 1];
    if (nB > 0) i2 = csr[bB + jB];
    if (nB > 1) i3 = csr[bB + jB + 1];
    if (nA > 0) {
      u16x8 v = *(const u16x8*)&hc[(size_t)i0*F];
#pragma unroll
      for (int u = 0; u < 8; u++) aA[u] += b2f(v[u]);
    }
    if (nA > 1) {
      u16x8 v = *(const u16x8*)&hc[(size_t)i1*F];
#pragma unroll
      for (int u = 0; u < 8; u++) aA[u] += b2f(v[u]);
    }
    if (nB > 0) {
      u16x8 v = *(const u16x8*)&hc[(size_t)i2*F];
#pragma unroll
      for (int u = 0; u < 8; u++) aB[u] += b2f(v[u]);
    }
    if (nB > 1) {
      u16x8 v = *(const u16x8*)&hc[(size_t)i3*F];
#pragma unroll
      for (int u = 0; u < 8; u++) aB[u] += b2f(v[u]);
    }
    jA += nA; jB += nB;
  }
  float ivA = cA ? 1.f/(float)cA : 0.f;
  float ivB = cB ? 1.f/(float)cB : 0.f;
  u16x8 oA, oB;
#pragma unroll
  for (int u = 0; u < 8; u++) { oA[u] = bf16r(aA[u]*ivA); oB[u] = bf16r(aB[u]*ivB); }
  *(u16x8*)&Mean[(size_t)(s0 - segBase)*F + c8] = oA;
  *(u16x8*)&Mean[(size_t)(s1 - segBase)*F + c8] = oB;
}

// ------------------- GEMM (+BN stats / +L2 norm) -------------------
// C[count x 128] = [Mean | hb_self] @ WB + bias. Mean K-rows 0..1023 (8 rel),
// root-term rows 1024..1151 read directly from hb. mode 0: BN stats; mode 1:
// fused row L2-normalize.
__global__ __launch_bounds__(256) void k_gemm(const unsigned short* __restrict__ Mean,
    const unsigned short* __restrict__ hb, const unsigned short* __restrict__ WB,
    const float* __restrict__ bias, float* __restrict__ outp,
    float* __restrict__ stats, int outBase, int count, int mode) {
  __shared__ float s_sum[128];
  __shared__ float s_sq[128];
  int t = threadIdx.x;
  int wave = t >> 6;
  int lane = t & 63;
  int rbase = blockIdx.x*128 + wave*32;
  int rlo = lane & 15;
  int kg = lane >> 4;
  int r0 = rbase + rlo;       if (r0 > count-1) r0 = count-1;
  int r1 = rbase + 16 + rlo;  if (r1 > count-1) r1 = count-1;
  const unsigned short* a0p = Mean + (size_t)r0*1024 + kg*8;
  const unsigned short* a1p = Mean + (size_t)r1*1024 + kg*8;
  const unsigned short* s0p = hb + (size_t)(outBase + r0)*F + kg*8;
  const unsigned short* s1p = hb + (size_t)(outBase + r1)*F + kg*8;
  const unsigned short* bp  = WB + (size_t)lane*8;

  if (mode == 0 && t < 128) { s_sum[t] = 0.f; s_sq[t] = 0.f; }

  f32x4 acc[2][8];
#pragma unroll
  for (int i = 0; i < 2; i++)
#pragma unroll
    for (int j = 0; j < 8; j++) acc[i][j] = (f32x4){0.f,0.f,0.f,0.f};

#pragma unroll 4
  for (int kt = 0; kt < 32; kt++) {
    bf16x8 a0 = *(const bf16x8*)(a0p + kt*32);
    bf16x8 a1 = *(const bf16x8*)(a1p + kt*32);
#pragma unroll
    for (int ct = 0; ct < 8; ct++) {
      bf16x8 b = *(const bf16x8*)(bp + (size_t)(kt*8 + ct)*64*8);
      acc[0][ct] = __builtin_amdgcn_mfma_f32_16x16x32_bf16(a0, b, acc[0][ct], 0, 0, 0);
      acc[1][ct] = __builtin_amdgcn_mfma_f32_16x16x32_bf16(a1, b, acc[1][ct], 0, 0, 0);
    }
  }
#pragma unroll
  for (int kt = 32; kt < 36; kt++) {
    bf16x8 a0 = *(const bf16x8*)(s0p + (kt-32)*32);
    bf16x8 a1 = *(const bf16x8*)(s1p + (kt-32)*32);
#pragma unroll
    for (int ct = 0; ct < 8; ct++) {
      bf16x8 b = *(const bf16x8*)(bp + (size_t)(kt*8 + ct)*64*8);
      acc[0][ct] = __builtin_amdgcn_mfma_f32_16x16x32_bf16(a0, b, acc[0][ct], 0, 0, 0);
      acc[1][ct] = __builtin_amdgcn_mfma_f32_16x16x32_bf16(a1, b, acc[1][ct], 0, 0, 0);
    }
  }

  float bv[8];
#pragma unroll
  for (int ct = 0; ct < 8; ct++) bv[ct] = bias[ct*16 + rlo];

  // C/D layout: col = ct*16 + rlo, row = rt*16 + kg*4 + i
  if (mode == 0) {
    __syncthreads();
    float psum[8], psq[8];
#pragma unroll
    for (int ct = 0; ct < 8; ct++) { psum[ct] = 0.f; psq[ct] = 0.f; }
#pragma unroll
    for (int rt = 0; rt < 2; rt++) {
#pragma unroll
      for (int i = 0; i < 4; i++) {
        int row = rbase + rt*16 + kg*4 + i;
        if (row < count) {
          float* orow = outp + (size_t)(outBase + row)*F;
#pragma unroll
          for (int ct = 0; ct < 8; ct++) {
            float y = acc[rt][ct][i] + bv[ct];
            orow[ct*16 + rlo] = y;
            psum[ct] += y;
            psq[ct]  += y*y;
          }
        }
      }
    }
#pragma unroll
    for (int ct = 0; ct < 8; ct++) {
      atomicAdd(&s_sum[ct*16 + rlo], psum[ct]);
      atomicAdd(&s_sq [ct*16 + rlo], psq[ct]);
    }
    __syncthreads();
    if (t < 128) {
      atomicAdd(&stats[t],       s_sum[t]);
      atomicAdd(&stats[128 + t], s_sq[t]);
    }
  } else {
#pragma unroll
    for (int rt = 0; rt < 2; rt++) {
#pragma unroll
      for (int i = 0; i < 4; i++) {
        int row = rbase + rt*16 + kg*4 + i;
        float y[8], ss = 0.f;
#pragma unroll
        for (int ct = 0; ct < 8; ct++) {
          y[ct] = acc[rt][ct][i] + bv[ct];
          ss += y[ct]*y[ct];
        }
#pragma unroll
        for (int m = 1; m < 16; m <<= 1)
          ss += __shfl_xor(ss, m, 64);
        float inv = 1.f / fmaxf(sqrtf(ss), 1e-12f);
        if (row < count) {
          float* orow = outp + (size_t)(outBase + row)*F;
#pragma unroll
          for (int ct = 0; ct < 8; ct++)
            orow[ct*16 + rlo] = y[ct]*inv;
        }
      }
    }
  }
}

// BN apply + LeakyReLU -> bf16 table for next layer
__global__ __launch_bounds__(256) void k_bnapply(const float* __restrict__ h,
    const float* __restrict__ stats, const float* __restrict__ gamma,
    const float* __restrict__ beta, unsigned short* __restrict__ outp) {
  int idx = blockIdx.x*256 + threadIdx.x;
  if (idx >= NN*32) return;
  int row = idx >> 5;
  int c4 = (idx & 31) * 4;
  float4 v  = *(const float4*)&h[(size_t)row*F + c4];
  float4 sm = *(const float4*)&stats[c4];
  float4 sq = *(const float4*)&stats[128 + c4];
  float4 gm = *(const float4*)&gamma[c4];
  float4 bt = *(const float4*)&beta[c4];
  const float invN = 1.f / (float)NN;
  ushort4 o;
  { float m = sm.x*invN; float var = sq.x*invN - m*m; float r0 = rsqrtf(var + BNEPS);
    float z = (v.x - m)*r0*gm.x + bt.x; o.x = bf16r((z > 0.f) ? z : 0.1f*z); }
  { float m = sm.y*invN; float var = sq.y*invN - m*m; float r0 = rsqrtf(var + BNEPS);
    float z = (v.y - m)*r0*gm.y + bt.y; o.y = bf16r((z > 0.f) ? z : 0.1f*z); }
  { float m = sm.z*invN; float var = sq.z*invN - m*m; float r0 = rsqrtf(var + BNEPS);
    float z = (v.z - m)*r0*gm.z + bt.z; o.z = bf16r((z > 0.f) ? z : 0.1f*z); }
  { float m = sm.w*invN; float var = sq.w*invN - m*m; float r0 = rsqrtf(var + BNEPS);
    float z = (v.w - m)*r0*gm.w + bt.w; o.w = bf16r((z > 0.f) ? z : 0.1f*z); }
  *(ushort4*)&outp[(size_t)row*F + c4] = o;
}

// ------------------- host launcher -------------------
extern "C" void kernel_launch(void* const* d_in, const int* in_sizes, int n_in,
                              void* d_out, int out_size, void* d_ws, size_t ws_size,
                              hipStream_t stream) {
  const float* x      = (const float*)d_in[0];
  const int*   ei     = (const int*)d_in[1];
  const int*   etp    = (const int*)d_in[2];
  const float* basis[3] = {(const float*)d_in[3], (const float*)d_in[7],  (const float*)d_in[11]};
  const float* comp[3]  = {(const float*)d_in[4], (const float*)d_in[8],  (const float*)d_in[12]};
  const float* root[3]  = {(const float*)d_in[5], (const float*)d_in[9],  (const float*)d_in[13]};
  const float* bias[3]  = {(const float*)d_in[6], (const float*)d_in[10], (const float*)d_in[14]};
  const float* gamma[2] = {(const float*)d_in[15], (const float*)d_in[17]};
  const float* beta[2]  = {(const float*)d_in[16], (const float*)d_in[18]};
  const int* srcv = ei;
  const int* dstv = ei + EE;
  float* out = (float*)d_out;

  char* w = (char*)d_ws;
  size_t p = 0;
  auto take = [&](size_t bytes) -> void* {
    void* q = w + p;
    p = (p + bytes + 255) & ~(size_t)255;
    return q;
  };
  unsigned* cnt   = (unsigned*)take((size_t)NSEG*4);
  unsigned* off   = (unsigned*)take((size_t)NSEG*4);
  int*      csr   = (int*)     take((size_t)EE*4);
  unsigned* bsum  = (unsigned*)take(1024*4);
  unsigned short* WB3 = (unsigned short*)take((size_t)3*1152*F*2);
  float*    stats = (float*)   take(512*4);
  float*    wsA   = (float*)   take((size_t)NN*F*4);             // f32 conv out
  unsigned short* wsBb = (unsigned short*)take((size_t)NN*F*2);  // bf16 BN out
  unsigned short* xb   = (unsigned short*)take((size_t)NN*F*2);  // bf16 x
  size_t avail = (ws_size > p) ? (ws_size - p) : 0;
  long long chmax = (long long)(avail / (1024*2));
  int CH = (chmax > NN) ? NN : (int)(chmax & ~3LL);
  if (CH < 4) CH = 4;
  unsigned short* Mean = (unsigned short*)(w + p);

  // -------- preprocessing --------
  hipMemsetAsync(cnt, 0, (size_t)NSEG*4, stream);
  k_precnt<<<12500, 256, 0, stream>>>(x, xb, dstv, etp, cnt);
  int nb1 = (NSEG + 2047)/2048;
  k_scan1<<<nb1, 256, 0, stream>>>(cnt, off, bsum);
  k_scan2<<<1, 512, 0, stream>>>(bsum, nb1);
  k_scan3<<<(NSEG+255)/256, 256, 0, stream>>>(off, bsum);
  k_fill<<<(EE+255)/256, 256, 0, stream>>>(srcv, dstv, etp, off, csr);
  dim3 gw(36, 8, 3);
  k_makeW3<<<gw, 64, 0, stream>>>(basis[0], comp[0], root[0],
                                  basis[1], comp[1], root[1],
                                  basis[2], comp[2], root[2], WB3, stats);

  // -------- 3 layers --------
  for (int l = 0; l < 3; l++) {
    const unsigned short* hin = (l == 0) ? xb : wsBb;
    float* hraw = (l == 2) ? out : wsA;
    int mode = (l == 2) ? 1 : 0;
    const unsigned short* WB = WB3 + (size_t)l*1152*F;
    float* st = stats + (size_t)(l == 2 ? 0 : l)*256;
    for (int b0n = 0; b0n < NN; b0n += CH) {
      int cc = NN - b0n; if (cc > CH) cc = CH;
      k_agg<<<cc*8/32, 256, 0, stream>>>(hin, off, cnt, csr, Mean, b0n*8);
      k_gemm<<<(cc+127)/128, 256, 0, stream>>>(Mean, hin, WB, bias[l], hraw, st, b0n, cc, mode);
    }
    if (l < 2)
      k_bnapply<<<12500, 256, 0, stream>>>(hraw, stats + (size_t)l*256, gamma[l], beta[l], wsBb);
  }
}

// Round 7
// 1066.269 us; speedup vs baseline: 1.7488x; 1.2370x over previous
//
#include <hip/hip_runtime.h>

#define NN 100000
#define EE 1600000
#define RRR 8
#define NSEG (NN*RRR)
#define F 128
#define KDIM 1152          // 8 relations * 128 + self(root) 128
#define NKT 36             // KDIM/32
#define BNEPS 1e-5f

typedef __attribute__((ext_vector_type(8))) short bf16x8;
typedef __attribute__((ext_vector_type(8))) unsigned short u16x8;
typedef __attribute__((ext_vector_type(4))) float f32x4;

static __device__ __forceinline__ unsigned short bf16r(float f) {
  unsigned u = __float_as_uint(f);
  u += 0x7fffu + ((u >> 16) & 1u);
  return (unsigned short)(u >> 16);
}
static __device__ __forceinline__ float b2f(unsigned short s) {
  return __uint_as_float((unsigned)s << 16);
}

// ------------------- preprocessing -------------------
// fused: bf16 convert of x  +  per-(dst,rel) segment count
__global__ __launch_bounds__(256) void k_precnt(const float* __restrict__ x,
    unsigned short* __restrict__ xb, const int* __restrict__ dst,
    const int* __restrict__ et, unsigned* __restrict__ cnt) {
  int idx = blockIdx.x*256 + threadIdx.x;
  if (idx < NN*32) {
    float4 v = ((const float4*)x)[idx];
    ushort4 o;
    o.x = bf16r(v.x); o.y = bf16r(v.y); o.z = bf16r(v.z); o.w = bf16r(v.w);
    ((ushort4*)xb)[idx] = o;
  }
  if (idx < EE)
    atomicAdd(&cnt[dst[idx]*RRR + et[idx]], 1u);
}

__global__ void k_scan1(const unsigned* __restrict__ cnt, unsigned* __restrict__ off,
                        unsigned* __restrict__ bsum) {
  __shared__ unsigned s[256];
  int t = threadIdx.x;
  int base = blockIdx.x*2048 + t*8;
  unsigned loc[8];
  unsigned tot = 0;
#pragma unroll
  for (int j = 0; j < 8; j++) {
    unsigned v = (base+j < NSEG) ? cnt[base+j] : 0u;
    loc[j] = tot;
    tot += v;
  }
  s[t] = tot;
  __syncthreads();
  for (int d = 1; d < 256; d <<= 1) {
    unsigned v = (t >= d) ? s[t-d] : 0u;
    __syncthreads();
    s[t] += v;
    __syncthreads();
  }
  unsigned tbase = s[t] - tot;
#pragma unroll
  for (int j = 0; j < 8; j++)
    if (base+j < NSEG) off[base+j] = tbase + loc[j];
  if (t == 255) bsum[blockIdx.x] = s[255];
}

__global__ void k_scan2(unsigned* bsum, int nb) {
  __shared__ unsigned s[512];
  int t = threadIdx.x;
  unsigned v = (t < nb) ? bsum[t] : 0u;
  s[t] = v;
  __syncthreads();
  for (int d = 1; d < 512; d <<= 1) {
    unsigned u = (t >= d) ? s[t-d] : 0u;
    __syncthreads();
    s[t] += u;
    __syncthreads();
  }
  if (t < nb) bsum[t] = (t == 0) ? 0u : s[t-1];
}

__global__ void k_scan3(unsigned* off, const unsigned* __restrict__ bsum) {
  int i = blockIdx.x*256 + threadIdx.x;
  if (i < NSEG) off[i] += bsum[i >> 11];
}

// fill using off itself as cursor: afterwards off[seg] = segment END;
// consumers recover start = off[seg] - cnt[seg].
__global__ void k_fill(const int* __restrict__ src, const int* __restrict__ dst,
                       const int* __restrict__ et, unsigned* __restrict__ off,
                       int* __restrict__ csr) {
  int e = blockIdx.x*256 + threadIdx.x;
  if (e < EE) {
    int seg = dst[e]*RRR + et[e];
    unsigned pos = atomicAdd(&off[seg], 1u);
    csr[pos] = src[e];
  }
}

// All 3 layers' weights in B-fragment layout, one launch; block(0,0,0)
// also zeroes both BN stats buffers.
__global__ void k_makeW3(const float* __restrict__ b1, const float* __restrict__ c1,
                         const float* __restrict__ r1, const float* __restrict__ b2,
                         const float* __restrict__ c2, const float* __restrict__ r2,
                         const float* __restrict__ b3, const float* __restrict__ c3,
                         const float* __restrict__ r3, unsigned short* __restrict__ WB3,
                         float* __restrict__ stats) {
  int kt = blockIdx.x, ct = blockIdx.y, l = blockIdx.z;
  int lane = threadIdx.x;
  if (kt == 0 && ct == 0 && l == 0) {
#pragma unroll
    for (int j = 0; j < 8; j++) stats[lane*8 + j] = 0.f;
  }
  const float* basis = (l == 0) ? b1 : (l == 1) ? b2 : b3;
  const float* comp  = (l == 0) ? c1 : (l == 1) ? c2 : c3;
  const float* root  = (l == 0) ? r1 : (l == 1) ? r2 : r3;
  int o = ct*16 + (lane & 15);
  int kbase = kt*32 + (lane >> 4)*8;
  unsigned short v[8];
#pragma unroll
  for (int j = 0; j < 8; j++) {
    int k = kbase + j;
    float val;
    if (k < 1024) {
      int r = k >> 7, i = k & 127;
      val = 0.f;
#pragma unroll
      for (int bb = 0; bb < 8; bb++)
        val += comp[r*8+bb] * basis[(bb*F + i)*F + o];
    } else {
      val = root[(k - 1024)*F + o];
    }
    v[j] = bf16r(val);
  }
  unsigned short* dstp = WB3 + (size_t)l*KDIM*F + ((size_t)(kt*8 + ct)*64 + lane)*8;
#pragma unroll
  for (int j = 0; j < 8; j++) dstp[j] = v[j];
}

// ------------------- aggregation -------------------
// Block = 32 segments (4 nodes). Group g (16 lanes) interleaves TWO segments
// -> up to 4 independent gathers in flight. Mean row = [node][KDIM]:
// relations at r*128, self row at 1024 (written by the r==0 groups).
__global__ __launch_bounds__(256) void k_agg(const unsigned short* __restrict__ hb,
    const unsigned* __restrict__ off, const unsigned* __restrict__ cnt,
    const int* __restrict__ csr, unsigned short* __restrict__ Mean, int segBase) {
  int t = threadIdx.x;
  int sl = t & 15, c8 = sl*8;
  int g = t >> 4;
  int s0 = segBase + blockIdx.x*32 + 2*g;
  int s1 = s0 + 1;
  unsigned cA = cnt[s0], cB = cnt[s1];
  unsigned bA = off[s0] - cA, bB = off[s1] - cB;
  const unsigned short* hc = hb + c8;
  float aA[8], aB[8];
#pragma unroll
  for (int u = 0; u < 8; u++) { aA[u] = 0.f; aB[u] = 0.f; }
  unsigned jA = 0, jB = 0;
  while (jA < cA || jB < cB) {
    unsigned nA = cA - jA; if (nA > 2) nA = 2;
    unsigned nB = cB - jB; if (nB > 2) nB = 2;
    int i0 = 0, i1 = 0, i2 = 0, i3 = 0;
    if (nA > 0) i0 = csr[bA + jA];
    if (nA > 1) i1 = csr[bA + jA + 1];
    if (nB > 0) i2 = csr[bB + jB];
    if (nB > 1) i3 = csr[bB + jB + 1];
    if (nA > 0) {
      u16x8 v = *(const u16x8*)&hc[(size_t)i0*F];
#pragma unroll
      for (int u = 0; u < 8; u++) aA[u] += b2f(v[u]);
    }
    if (nA > 1) {
      u16x8 v = *(const u16x8*)&hc[(size_t)i1*F];
#pragma unroll
      for (int u = 0; u < 8; u++) aA[u] += b2f(v[u]);
    }
    if (nB > 0) {
      u16x8 v = *(const u16x8*)&hc[(size_t)i2*F];
#pragma unroll
      for (int u = 0; u < 8; u++) aB[u] += b2f(v[u]);
    }
    if (nB > 1) {
      u16x8 v = *(const u16x8*)&hc[(size_t)i3*F];
#pragma unroll
      for (int u = 0; u < 8; u++) aB[u] += b2f(v[u]);
    }
    jA += nA; jB += nB;
  }
  float ivA = cA ? 1.f/(float)cA : 0.f;
  float ivB = cB ? 1.f/(float)cB : 0.f;
  u16x8 oA, oB;
#pragma unroll
  for (int u = 0; u < 8; u++) { oA[u] = bf16r(aA[u]*ivA); oB[u] = bf16r(aB[u]*ivB); }
  int l0 = s0 - segBase, l1 = s1 - segBase;
  *(u16x8*)&Mean[(size_t)(l0 >> 3)*KDIM + (l0 & 7)*F + c8] = oA;
  *(u16x8*)&Mean[(size_t)(l1 >> 3)*KDIM + (l1 & 7)*F + c8] = oB;
  if ((s0 & 7) == 0) {   // this group owns relation 0 of its node: write self row
    int node = s0 >> 3;
    *(u16x8*)&Mean[(size_t)(l0 >> 3)*KDIM + 1024 + c8] =
        *(const u16x8*)&hb[(size_t)node*F + c8];
  }
}

// ------------------- GEMM (+BN stats / +L2 norm) -------------------
// Round-4-proven config: single Mean source, 2304 B row stride, plain kt loop.
// mode 0: BN stats accumulate. mode 1: fused row L2-normalize (final layer).
__global__ __launch_bounds__(256) void k_gemm(const unsigned short* __restrict__ Mean,
    const unsigned short* __restrict__ WB, const float* __restrict__ bias,
    float* __restrict__ outp, float* __restrict__ stats,
    int outBase, int count, int mode) {
  __shared__ float s_sum[128];
  __shared__ float s_sq[128];
  int t = threadIdx.x;
  int wave = t >> 6;
  int lane = t & 63;
  int rbase = blockIdx.x*128 + wave*32;
  int rlo = lane & 15;
  int kg = lane >> 4;
  int r0 = rbase + rlo;       if (r0 > count-1) r0 = count-1;
  int r1 = rbase + 16 + rlo;  if (r1 > count-1) r1 = count-1;
  const unsigned short* a0p = Mean + (size_t)r0*KDIM + kg*8;
  const unsigned short* a1p = Mean + (size_t)r1*KDIM + kg*8;
  const unsigned short* bp  = WB + (size_t)lane*8;

  if (mode == 0 && t < 128) { s_sum[t] = 0.f; s_sq[t] = 0.f; }

  f32x4 acc[2][8];
#pragma unroll
  for (int i = 0; i < 2; i++)
#pragma unroll
    for (int j = 0; j < 8; j++) acc[i][j] = (f32x4){0.f,0.f,0.f,0.f};

  for (int kt = 0; kt < NKT; kt++) {
    bf16x8 a0 = *(const bf16x8*)(a0p + kt*32);
    bf16x8 a1 = *(const bf16x8*)(a1p + kt*32);
#pragma unroll
    for (int ct = 0; ct < 8; ct++) {
      bf16x8 b = *(const bf16x8*)(bp + (size_t)(kt*8 + ct)*64*8);
      acc[0][ct] = __builtin_amdgcn_mfma_f32_16x16x32_bf16(a0, b, acc[0][ct], 0, 0, 0);
      acc[1][ct] = __builtin_amdgcn_mfma_f32_16x16x32_bf16(a1, b, acc[1][ct], 0, 0, 0);
    }
  }

  float bv[8];
#pragma unroll
  for (int ct = 0; ct < 8; ct++) bv[ct] = bias[ct*16 + rlo];

  // C/D layout: col = ct*16 + rlo, row = rt*16 + kg*4 + i
  if (mode == 0) {
    __syncthreads();
    float psum[8], psq[8];
#pragma unroll
    for (int ct = 0; ct < 8; ct++) { psum[ct] = 0.f; psq[ct] = 0.f; }
#pragma unroll
    for (int rt = 0; rt < 2; rt++) {
#pragma unroll
      for (int i = 0; i < 4; i++) {
        int row = rbase + rt*16 + kg*4 + i;
        if (row < count) {
          float* orow = outp + (size_t)(outBase + row)*F;
#pragma unroll
          for (int ct = 0; ct < 8; ct++) {
            float y = acc[rt][ct][i] + bv[ct];
            orow[ct*16 + rlo] = y;
            psum[ct] += y;
            psq[ct]  += y*y;
          }
        }
      }
    }
#pragma unroll
    for (int ct = 0; ct < 8; ct++) {
      atomicAdd(&s_sum[ct*16 + rlo], psum[ct]);
      atomicAdd(&s_sq [ct*16 + rlo], psq[ct]);
    }
    __syncthreads();
    if (t < 128) {
      atomicAdd(&stats[t],       s_sum[t]);
      atomicAdd(&stats[128 + t], s_sq[t]);
    }
  } else {
#pragma unroll
    for (int rt = 0; rt < 2; rt++) {
#pragma unroll
      for (int i = 0; i < 4; i++) {
        int row = rbase + rt*16 + kg*4 + i;
        float y[8], ss = 0.f;
#pragma unroll
        for (int ct = 0; ct < 8; ct++) {
          y[ct] = acc[rt][ct][i] + bv[ct];
          ss += y[ct]*y[ct];
        }
#pragma unroll
        for (int m = 1; m < 16; m <<= 1)
          ss += __shfl_xor(ss, m, 64);
        float inv = 1.f / fmaxf(sqrtf(ss), 1e-12f);
        if (row < count) {
          float* orow = outp + (size_t)(outBase + row)*F;
#pragma unroll
          for (int ct = 0; ct < 8; ct++)
            orow[ct*16 + rlo] = y[ct]*inv;
        }
      }
    }
  }
}

// BN apply + LeakyReLU -> bf16 table for next layer
__global__ __launch_bounds__(256) void k_bnapply(const float* __restrict__ h,
    const float* __restrict__ stats, const float* __restrict__ gamma,
    const float* __restrict__ beta, unsigned short* __restrict__ outp) {
  int idx = blockIdx.x*256 + threadIdx.x;
  if (idx >= NN*32) return;
  int row = idx >> 5;
  int c4 = (idx & 31) * 4;
  float4 v  = *(const float4*)&h[(size_t)row*F + c4];
  float4 sm = *(const float4*)&stats[c4];
  float4 sq = *(const float4*)&stats[128 + c4];
  float4 gm = *(const float4*)&gamma[c4];
  float4 bt = *(const float4*)&beta[c4];
  const float invN = 1.f / (float)NN;
  ushort4 o;
  { float m = sm.x*invN; float var = sq.x*invN - m*m; float r0 = rsqrtf(var + BNEPS);
    float z = (v.x - m)*r0*gm.x + bt.x; o.x = bf16r((z > 0.f) ? z : 0.1f*z); }
  { float m = sm.y*invN; float var = sq.y*invN - m*m; float r0 = rsqrtf(var + BNEPS);
    float z = (v.y - m)*r0*gm.y + bt.y; o.y = bf16r((z > 0.f) ? z : 0.1f*z); }
  { float m = sm.z*invN; float var = sq.z*invN - m*m; float r0 = rsqrtf(var + BNEPS);
    float z = (v.z - m)*r0*gm.z + bt.z; o.z = bf16r((z > 0.f) ? z : 0.1f*z); }
  { float m = sm.w*invN; float var = sq.w*invN - m*m; float r0 = rsqrtf(var + BNEPS);
    float z = (v.w - m)*r0*gm.w + bt.w; o.w = bf16r((z > 0.f) ? z : 0.1f*z); }
  *(ushort4*)&outp[(size_t)row*F + c4] = o;
}

// ------------------- host launcher -------------------
extern "C" void kernel_launch(void* const* d_in, const int* in_sizes, int n_in,
                              void* d_out, int out_size, void* d_ws, size_t ws_size,
                              hipStream_t stream) {
  const float* x      = (const float*)d_in[0];
  const int*   ei     = (const int*)d_in[1];
  const int*   etp    = (const int*)d_in[2];
  const float* basis[3] = {(const float*)d_in[3], (const float*)d_in[7],  (const float*)d_in[11]};
  const float* comp[3]  = {(const float*)d_in[4], (const float*)d_in[8],  (const float*)d_in[12]};
  const float* root[3]  = {(const float*)d_in[5], (const float*)d_in[9],  (const float*)d_in[13]};
  const float* bias[3]  = {(const float*)d_in[6], (const float*)d_in[10], (const float*)d_in[14]};
  const float* gamma[2] = {(const float*)d_in[15], (const float*)d_in[17]};
  const float* beta[2]  = {(const float*)d_in[16], (const float*)d_in[18]};
  const int* srcv = ei;
  const int* dstv = ei + EE;
  float* out = (float*)d_out;

  char* w = (char*)d_ws;
  size_t p = 0;
  auto take = [&](size_t bytes) -> void* {
    void* q = w + p;
    p = (p + bytes + 255) & ~(size_t)255;
    return q;
  };
  unsigned* cnt   = (unsigned*)take((size_t)NSEG*4);
  unsigned* off   = (unsigned*)take((size_t)NSEG*4);
  int*      csr   = (int*)     take((size_t)EE*4);
  unsigned* bsum  = (unsigned*)take(1024*4);
  unsigned short* WB3 = (unsigned short*)take((size_t)3*KDIM*F*2);
  float*    stats = (float*)   take(512*4);
  float*    wsA   = (float*)   take((size_t)NN*F*4);             // f32 conv out
  unsigned short* wsBb = (unsigned short*)take((size_t)NN*F*2);  // bf16 BN out
  unsigned short* xb   = (unsigned short*)take((size_t)NN*F*2);  // bf16 x
  size_t avail = (ws_size > p) ? (ws_size - p) : 0;
  long long chmax = (long long)(avail / ((size_t)KDIM*2));
  int CH = (chmax > NN) ? NN : (int)(chmax & ~3LL);
  if (CH < 4) CH = 4;
  unsigned short* Mean = (unsigned short*)(w + p);

  // -------- preprocessing --------
  hipMemsetAsync(cnt, 0, (size_t)NSEG*4, stream);
  k_precnt<<<12500, 256, 0, stream>>>(x, xb, dstv, etp, cnt);
  int nb1 = (NSEG + 2047)/2048;
  k_scan1<<<nb1, 256, 0, stream>>>(cnt, off, bsum);
  k_scan2<<<1, 512, 0, stream>>>(bsum, nb1);
  k_scan3<<<(NSEG+255)/256, 256, 0, stream>>>(off, bsum);
  k_fill<<<(EE+255)/256, 256, 0, stream>>>(srcv, dstv, etp, off, csr);
  dim3 gw(NKT, 8, 3);
  k_makeW3<<<gw, 64, 0, stream>>>(basis[0], comp[0], root[0],
                                  basis[1], comp[1], root[1],
                                  basis[2], comp[2], root[2], WB3, stats);

  // -------- 3 layers --------
  for (int l = 0; l < 3; l++) {
    const unsigned short* hin = (l == 0) ? xb : wsBb;
    float* hraw = (l == 2) ? out : wsA;
    int mode = (l == 2) ? 1 : 0;
    const unsigned short* WB = WB3 + (size_t)l*KDIM*F;
    float* st = stats + (size_t)(l == 2 ? 0 : l)*256;
    for (int b0n = 0; b0n < NN; b0n += CH) {
      int cc = NN - b0n; if (cc > CH) cc = CH;
      k_agg<<<cc/4, 256, 0, stream>>>(hin, off, cnt, csr, Mean, b0n*8);
      k_gemm<<<(cc+127)/128, 256, 0, stream>>>(Mean, WB, bias[l], hraw, st, b0n, cc, mode);
    }
    if (l < 2)
      k_bnapply<<<12500, 256, 0, stream>>>(hraw, stats + (size_t)l*256, gamma[l], beta[l], wsBb);
  }
}